// Round 3
// baseline (444.923 us; speedup 1.0000x reference)
//
#include <hip/hip_runtime.h>
#include <cstdint>

typedef unsigned short u16;
typedef unsigned int u32;

typedef __attribute__((ext_vector_type(8))) short bf16x8;
typedef __attribute__((ext_vector_type(4))) float f32x4;

// x: (32,128,112,112) f32 ; routing_w: (4,128) ; routing_b: (4,)
// expert_weight: (4,256,128,3,3) ; out: (32,256,56,56) f32
#define KDIM 1152       // 9*128, k = (kh*3+kw)*128 + ci  (tap-major)
#define MDIM 256
#define NPIX 3136
#define PLANE 12544     // 112*112
#define EWSTRIDE 294912 // 256*1152
#define HH 114          // haloed spatial dim
#define XT_SAMP ((size_t)HH * HH * 128)  // u16 per sample

__device__ __forceinline__ u16 f2bf(float f) {
  u32 u = __float_as_uint(f);
  return (u16)((u + 0x7FFFu + ((u >> 16) & 1u)) >> 16);
}

__device__ __forceinline__ void gl_lds16(const u16* g, u16* l) {
  __builtin_amdgcn_global_load_lds((__attribute__((address_space(1))) void*)g,
                                   (__attribute__((address_space(3))) void*)l,
                                   16, 0, 0);
}

// ---- transpose NCHW f32 -> NHWC-halo bf16, fused pool partials + halo zeroing ----
// grid (112 h, 32 b), 256 thr. Block: all 128 ci x 112 w of one (b,h) row.
// float2 reads along w: lane l (l<56) owns w = 2l, 2l+1 -> 8B/lane global loads.
__global__ __launch_bounds__(256) void transpose_pool_kernel(
    const float* __restrict__ x, u16* __restrict__ xt, float* __restrict__ part) {
  __shared__ u32 tile[112 * 68];   // [w][ci/2], stride 68 words (16B aligned rows)
  __shared__ float psum[512];
  const int h = blockIdx.x, b = blockIdx.y;
  const int t = threadIdx.x, lane = t & 63, wave = t >> 6;

  // fused halo: zero w=0 / w=113 of this block's output row (h+1)
  {
    u32* xrow = (u32*)xt + ((size_t)b * HH + (h + 1)) * HH * 64;
    if (t < 128) {
      const int w = (t >= 64) ? 113 : 0;
      xrow[(size_t)w * 64 + (t & 63)] = 0u;
    }
    // blocks h==0 / h==111 additionally zero full border rows 0 / 113
    if (h == 0 || h == 111) {
      u32* xr = (u32*)xt + ((size_t)b * HH + (h == 0 ? 0 : 113)) * HH * 64;
      for (int i = t; i < HH * 64; i += 256) xr[i] = 0u;
    }
  }

  const float* xb = x + (size_t)b * 128 * PLANE + h * 112;
  if (lane < 56) {
    const int w0 = 2 * lane;
    #pragma unroll
    for (int i = 0; i < 4; ++i) {
      const int ci0 = (i * 4 + wave) * 8;
      const float* p = xb + (size_t)ci0 * PLANE + w0;
      float2 q0 = *(const float2*)(p);
      float2 q1 = *(const float2*)(p + (size_t)1 * PLANE);
      float2 q2 = *(const float2*)(p + (size_t)2 * PLANE);
      float2 q3 = *(const float2*)(p + (size_t)3 * PLANE);
      float2 q4 = *(const float2*)(p + (size_t)4 * PLANE);
      float2 q5 = *(const float2*)(p + (size_t)5 * PLANE);
      float2 q6 = *(const float2*)(p + (size_t)6 * PLANE);
      float2 q7 = *(const float2*)(p + (size_t)7 * PLANE);
      uint4 dE, dO;
      dE.x = (u32)f2bf(q0.x) | ((u32)f2bf(q1.x) << 16);
      dO.x = (u32)f2bf(q0.y) | ((u32)f2bf(q1.y) << 16);
      dE.y = (u32)f2bf(q2.x) | ((u32)f2bf(q3.x) << 16);
      dO.y = (u32)f2bf(q2.y) | ((u32)f2bf(q3.y) << 16);
      dE.z = (u32)f2bf(q4.x) | ((u32)f2bf(q5.x) << 16);
      dO.z = (u32)f2bf(q4.y) | ((u32)f2bf(q5.y) << 16);
      dE.w = (u32)f2bf(q6.x) | ((u32)f2bf(q7.x) << 16);
      dO.w = (u32)f2bf(q6.y) | ((u32)f2bf(q7.y) << 16);
      *(uint4*)&tile[(size_t)w0 * 68 + ci0 / 2] = dE;
      *(uint4*)&tile[(size_t)(w0 + 1) * 68 + ci0 / 2] = dO;
    }
  }
  __syncthreads();
  // write out contiguous 112*64 u32; accumulate fp32 pool sums (thread owns ci pair)
  const int c = t & 63;
  float s0 = 0.f, s1 = 0.f;
  u32* xg = (u32*)xt + (((size_t)b * HH + h + 1) * HH + 1) * 64;
  #pragma unroll
  for (int j = 0; j < 28; ++j) {
    const int idx = t + 256 * j;
    const int w = idx >> 6;
    const u32 v = tile[w * 68 + c];
    s0 += __uint_as_float(v << 16);
    s1 += __uint_as_float(v & 0xffff0000u);
    xg[(size_t)w * 64 + c] = v;
  }
  psum[wave * 128 + 2 * c] = s0;
  psum[wave * 128 + 2 * c + 1] = s1;
  __syncthreads();
  if (t < 128)
    part[((size_t)h * 32 + b) * 128 + t] =
        psum[t] + psum[128 + t] + psum[256 + t] + psum[384 + t];
}

// ---- fused reduce-over-h + routing. grid 32 (b), 256 thr ----
__global__ __launch_bounds__(256) void reduce_routing_kernel(
    const float* __restrict__ part, const float* __restrict__ rww,
    const float* __restrict__ rwb, float* __restrict__ rw) {
  __shared__ float red[256];
  __shared__ float pl[128];
  const int b = blockIdx.x, t = threadIdx.x;
  const int ci = t & 127, half = t >> 7;
  float s = 0.f;
  const float* p = part + ((size_t)(half * 56) * 32 + b) * 128 + ci;
  #pragma unroll 4
  for (int h = 0; h < 56; ++h) s += p[(size_t)h * 32 * 128];
  red[t] = s;
  __syncthreads();
  if (t < 128) pl[t] = red[t] + red[t + 128];
  __syncthreads();
  const int e = t >> 6, l = t & 63;
  float acc = pl[l] * rww[e * 128 + l] + pl[l + 64] * rww[e * 128 + l + 64];
  #pragma unroll
  for (int off = 32; off > 0; off >>= 1) acc += __shfl_down(acc, off, 64);
  if (l == 0) {
    const float logit = acc * (1.0f / (float)PLANE) + rwb[e];
    rw[b * 4 + e] = 1.0f / (1.0f + expf(-logit));
  }
}

// ---- mix: Wmix[b][oc][(kh*3+kw)*128+ci] = sum_e rw[b,e]*ew[e][oc][ci][kh,kw]
// grid (64 ocgrp, 8 bgrp): 512 blocks -> 2/CU for latency hiding
__global__ __launch_bounds__(256) void mix_kernel(const float* __restrict__ ew,
                                                  const float* __restrict__ rw,
                                                  u16* __restrict__ wmix) {
  const int t = threadIdx.x;
  const int oc = blockIdx.x * 4 + (t >> 6);
  const int lane = t & 63;
  const int b0 = blockIdx.y * 4;
  float ereg[4][18];
  #pragma unroll
  for (int e = 0; e < 4; ++e) {
    const float* p = ew + ((size_t)e * 256 + oc) * 1152 + lane * 18;
    #pragma unroll
    for (int j = 0; j < 18; ++j) ereg[e][j] = p[j];
  }
  for (int bb = 0; bb < 4; ++bb) {
    const int b = b0 + bb;
    const float w0 = rw[b * 4 + 0], w1 = rw[b * 4 + 1];
    const float w2 = rw[b * 4 + 2], w3 = rw[b * 4 + 3];
    u32* dst = (u32*)(wmix + ((size_t)b * 256 + oc) * KDIM) + lane;
    #pragma unroll
    for (int r = 0; r < 9; ++r) {
      const float va = w0 * ereg[0][r] + w1 * ereg[1][r] + w2 * ereg[2][r] + w3 * ereg[3][r];
      const float vb = w0 * ereg[0][9 + r] + w1 * ereg[1][9 + r] + w2 * ereg[2][9 + r] + w3 * ereg[3][9 + r];
      dst[r * 64] = (u32)f2bf(va) | ((u32)f2bf(vb) << 16);
    }
  }
}

// ---- GEMM with implicit im2col. grid (32 b, 50 tiles): id ≡ b (mod 8) -> XCD locality
// T3-minimal prefetch pipeline: stage tile t+1 BEFORE computing tile t, one
// vmcnt(0)+barrier per K-tile (18 total). Loads fly under the 32-MFMA block.
// LDS: 2 sets x (A 16KB + B 16KB) = 64KB -> 2 blocks/CU.
__global__ __launch_bounds__(256) void gemm_kernel(const u16* __restrict__ wmix,
                                                   const u16* __restrict__ xt,
                                                   float* __restrict__ out) {
  __shared__ u16 a_sm[2][2][128 * 32];   // [set][k-chunk][row*32 + k]
  __shared__ u16 b_sm[2][2][128 * 32];
  const int b = blockIdx.x;
  const int mt = blockIdx.y & 1, nt = blockIdx.y >> 1;
  const int tid = threadIdx.x, lane = tid & 63, wave = tid >> 6;
  const int srow = lane >> 2, scol = (lane & 3) * 8;
  const u16* ga0 = wmix + (size_t)b * EWSTRIDE + (size_t)(mt * 128 + wave * 16 + srow) * KDIM + scol;
  const u16* ga1 = ga0 + 64 * KDIM;
  const u16* xtb = xt + (size_t)b * XT_SAMP;
  int p0 = nt * 128 + wave * 16 + (lane >> 2);
  int p1 = p0 + 64;
  if (p0 > NPIX - 1) p0 = NPIX - 1;
  if (p1 > NPIX - 1) p1 = NPIX - 1;
  const size_t pb0 = ((size_t)(2 * (p0 / 56)) * HH + 2 * (p0 % 56)) * 128 + scol;
  const size_t pb1 = ((size_t)(2 * (p1 / 56)) * HH + 2 * (p1 % 56)) * 128 + scol;

  u16* const la = &a_sm[0][0][wave * 512 + lane * 8];  // +S*8192 set, +4096 chunk
  u16* const lb = &b_sm[0][0][wave * 512 + lane * 8];

  const int wm = wave >> 1, wn = wave & 1;
  const int fr = lane & 15, quad = lane >> 4;
  f32x4 acc[4][4];
  const f32x4 zv = {0.f, 0.f, 0.f, 0.f};
  #pragma unroll
  for (int i = 0; i < 4; ++i)
    #pragma unroll
    for (int j = 0; j < 4; ++j) acc[i][j] = zv;

#define STAGE(S, KT) do {                                                      \
    const int k0_ = (KT) * 2;                                                  \
    const int r_ = k0_ >> 2;                                                   \
    const size_t tp_ = (size_t)((r_ / 3) * HH + (r_ % 3)) * 128                \
                     + (size_t)(k0_ & 3) * 32;                                 \
    const u16* a0_ = ga0 + k0_ * 32;                                           \
    const u16* a1_ = ga1 + k0_ * 32;                                           \
    const u16* b0_ = xtb + pb0 + tp_;                                          \
    const u16* b1_ = xtb + pb1 + tp_;                                          \
    u16* la_ = la + (S) * 8192;                                                \
    u16* lb_ = lb + (S) * 8192;                                                \
    gl_lds16(a0_, la_);                                                        \
    gl_lds16(a1_, la_ + 2048);                                                 \
    gl_lds16(a0_ + 32, la_ + 4096);                                            \
    gl_lds16(a1_ + 32, la_ + 6144);                                            \
    gl_lds16(b0_, lb_);                                                        \
    gl_lds16(b1_, lb_ + 2048);                                                 \
    gl_lds16(b0_ + 32, lb_ + 4096);                                            \
    gl_lds16(b1_ + 32, lb_ + 6144);                                            \
  } while (0)

#define COMPUTE(S) do {                                                        \
    _Pragma("unroll")                                                          \
    for (int c_ = 0; c_ < 2; ++c_) {                                           \
      const u16* as_ = &a_sm[S][c_][0];                                        \
      const u16* bs_ = &b_sm[S][c_][0];                                        \
      bf16x8 av[4], bv[4];                                                     \
      _Pragma("unroll")                                                        \
      for (int i = 0; i < 4; ++i)                                              \
        av[i] = *(const bf16x8*)(as_ + (wm * 64 + i * 16 + fr) * 32 + quad * 8);\
      _Pragma("unroll")                                                        \
      for (int j = 0; j < 4; ++j)                                              \
        bv[j] = *(const bf16x8*)(bs_ + (wn * 64 + j * 16 + fr) * 32 + quad * 8);\
      _Pragma("unroll")                                                        \
      for (int i = 0; i < 4; ++i)                                              \
        _Pragma("unroll")                                                      \
        for (int j = 0; j < 4; ++j)                                            \
          acc[i][j] = __builtin_amdgcn_mfma_f32_16x16x32_bf16(av[i], bv[j],    \
                                                              acc[i][j], 0, 0, 0);\
    }                                                                          \
  } while (0)

  // prologue: tile 0 -> set 0
  STAGE(0, 0);
  __syncthreads();
  for (int i = 0; i < 8; ++i) {
    STAGE(1, 2 * i + 1);   // prefetch odd tile under compute of even
    COMPUTE(0);
    __syncthreads();       // drains prefetch loads + handoff
    STAGE(0, 2 * i + 2);   // prefetch even tile under compute of odd
    COMPUTE(1);
    __syncthreads();
  }
  STAGE(1, 17);
  COMPUTE(0);              // tile 16
  __syncthreads();
  COMPUTE(1);              // tile 17

#undef STAGE
#undef COMPUTE

  float* os = out + (size_t)b * MDIM * NPIX;
  const int mbase = mt * 128 + wm * 64 + quad * 4;
  const int nb = nt * 128 + wn * 64 + fr;
  #pragma unroll
  for (int j = 0; j < 4; ++j) {
    const int n = nb + j * 16;
    if (n < NPIX) {
      #pragma unroll
      for (int i = 0; i < 4; ++i) {
        const int m = mbase + i * 16;
        #pragma unroll
        for (int rr = 0; rr < 4; ++rr)
          os[(size_t)(m + rr) * NPIX + n] = acc[i][j][rr];
      }
    }
  }
}

// ---- fallback path (ws too small): pool + naive direct conv ----
__global__ void routing_kernel(const float* __restrict__ pooled,
                               const float* __restrict__ rww,
                               const float* __restrict__ rwb,
                               float* __restrict__ rw, float scale) {
  const int t = threadIdx.x;
  if (t >= 128) return;
  const int b = t >> 2, e = t & 3;
  float acc = rwb[e];
  for (int c = 0; c < 128; ++c) acc += pooled[b * 128 + c] * scale * rww[e * 128 + c];
  rw[b * 4 + e] = 1.0f / (1.0f + expf(-acc));
}

__global__ __launch_bounds__(256) void pool_kernel(const float* __restrict__ x,
                                                   float* __restrict__ pooled) {
  const int ci = blockIdx.x, b = blockIdx.y;
  const float4* p = (const float4*)(x + ((size_t)b * 128 + ci) * PLANE);
  float s = 0.f;
  for (int i = threadIdx.x; i < PLANE / 4; i += 256) {
    float4 v = p[i];
    s += v.x + v.y + v.z + v.w;
  }
  #pragma unroll
  for (int off = 32; off > 0; off >>= 1) s += __shfl_down(s, off, 64);
  __shared__ float red[4];
  if ((threadIdx.x & 63) == 0) red[threadIdx.x >> 6] = s;
  __syncthreads();
  if (threadIdx.x == 0)
    pooled[b * 128 + ci] = (red[0] + red[1] + red[2] + red[3]) * (1.0f / (float)PLANE);
}

__global__ __launch_bounds__(256) void naive_conv(const float* __restrict__ x,
                                                  const float* __restrict__ ew,
                                                  const float* __restrict__ rw,
                                                  float* __restrict__ out) {
  const size_t idx = (size_t)blockIdx.x * 256 + threadIdx.x;
  if (idx >= (size_t)32 * MDIM * NPIX) return;
  const int n = (int)(idx % NPIX);
  const int tmp = (int)(idx / NPIX);
  const int oc = tmp % MDIM;
  const int b = tmp / MDIM;
  const int oh = n / 56, ow = n % 56;
  const float w0 = rw[b * 4 + 0], w1 = rw[b * 4 + 1];
  const float w2 = rw[b * 4 + 2], w3 = rw[b * 4 + 3];
  float acc = 0.f;
  for (int ci = 0; ci < 128; ++ci) {
    const float* xp = x + ((size_t)b * 128 + ci) * PLANE;
    const size_t wb = ((size_t)oc * 128 + ci) * 9;
    for (int kh = 0; kh < 3; ++kh) {
      const int ih = 2 * oh - 1 + kh;
      if (ih < 0 || ih >= 112) continue;
      for (int kw = 0; kw < 3; ++kw) {
        const int iw = 2 * ow - 1 + kw;
        if (iw < 0 || iw >= 112) continue;
        const int ko = kh * 3 + kw;
        const float wsum = w0 * ew[wb + ko] + w1 * ew[(size_t)EWSTRIDE + wb + ko]
                         + w2 * ew[2 * (size_t)EWSTRIDE + wb + ko]
                         + w3 * ew[3 * (size_t)EWSTRIDE + wb + ko];
        acc += xp[ih * 112 + iw] * wsum;
      }
    }
  }
  out[idx] = acc;
}

extern "C" void kernel_launch(void* const* d_in, const int* in_sizes, int n_in,
                              void* d_out, int out_size, void* d_ws, size_t ws_size,
                              hipStream_t stream) {
  const float* x   = (const float*)d_in[0];
  const float* rww = (const float*)d_in[1];
  const float* rwb = (const float*)d_in[2];
  const float* ew  = (const float*)d_in[3];
  float* out = (float*)d_out;

  const size_t xt_bytes = 32 * XT_SAMP * 2;                     // 106,463,232
  const size_t wmix_off = xt_bytes;
  const size_t part_off = wmix_off + (size_t)32 * EWSTRIDE * 2; // +18,874,368
  const size_t pooled_off = part_off + (size_t)112 * 32 * 128 * 4;  // +1,835,008
  const size_t rw_off = pooled_off + 16384;
  const size_t need = rw_off + 512;

  if (ws_size >= need) {
    u16* xt = (u16*)d_ws;
    u16* wmix = (u16*)((char*)d_ws + wmix_off);
    float* part = (float*)((char*)d_ws + part_off);
    float* rw_ws = (float*)((char*)d_ws + rw_off);
    transpose_pool_kernel<<<dim3(112, 32), 256, 0, stream>>>(x, xt, part);
    reduce_routing_kernel<<<32, 256, 0, stream>>>(part, rww, rwb, rw_ws);
    mix_kernel<<<dim3(64, 8), 256, 0, stream>>>(ew, rw_ws, wmix);
    gemm_kernel<<<dim3(32, 50), 256, 0, stream>>>(wmix, xt, out);
  } else {
    float* pooled = (float*)d_ws;
    float* rw_ws = (float*)((char*)d_ws + 16384);
    pool_kernel<<<dim3(128, 32), 256, 0, stream>>>(x, pooled);
    routing_kernel<<<1, 128, 0, stream>>>(pooled, rww, rwb, rw_ws, 1.0f);
    naive_conv<<<(int)(((size_t)32 * MDIM * NPIX + 255) / 256), 256, 0, stream>>>(
        x, ew, rw_ws, out);
  }
}

// Round 5
// 423.905 us; speedup vs baseline: 1.0496x; 1.0496x over previous
//
#include <hip/hip_runtime.h>
#include <cstdint>

typedef unsigned short u16;
typedef unsigned int u32;

typedef __attribute__((ext_vector_type(8))) short bf16x8;
typedef __attribute__((ext_vector_type(4))) float f32x4;

// x: (32,128,112,112) f32 ; routing_w: (4,128) ; routing_b: (4,)
// expert_weight: (4,256,128,3,3) ; out: (32,256,56,56) f32
#define KDIM 1152       // 9*128, k = (kh*3+kw)*128 + ci  (tap-major)
#define MDIM 256
#define NPIX 3136
#define PLANE 12544     // 112*112
#define EWSTRIDE 294912 // 256*1152 (u16 per sample of wmix, tiled layout)
#define HH 114          // haloed spatial dim
#define XT_SAMP ((size_t)HH * HH * 128)  // u16 per sample

__device__ __forceinline__ u16 f2bf(float f) {
  u32 u = __float_as_uint(f);
  return (u16)((u + 0x7FFFu + ((u >> 16) & 1u)) >> 16);
}

__device__ __forceinline__ void gl_lds16(const u16* g, u16* l) {
  __builtin_amdgcn_global_load_lds((__attribute__((address_space(1))) void*)g,
                                   (__attribute__((address_space(3))) void*)l,
                                   16, 0, 0);
}

// ---- transpose NCHW f32 -> NHWC-halo bf16, fused pool partials + halo zeroing ----
__global__ __launch_bounds__(256) void transpose_pool_kernel(
    const float* __restrict__ x, u16* __restrict__ xt, float* __restrict__ part) {
  __shared__ u32 tile[112 * 68];   // [w][ci/2], stride 68 words
  __shared__ float psum[512];
  const int h = blockIdx.x, b = blockIdx.y;
  const int t = threadIdx.x, lane = t & 63, wave = t >> 6;

  // fused halo: zero w=0 / w=113 of this block's output row (h+1)
  {
    u32* xrow = (u32*)xt + ((size_t)b * HH + (h + 1)) * HH * 64;
    if (t < 128) {
      const int w = (t >= 64) ? 113 : 0;
      xrow[(size_t)w * 64 + (t & 63)] = 0u;
    }
    if (h == 0 || h == 111) {
      u32* xr = (u32*)xt + ((size_t)b * HH + (h == 0 ? 0 : 113)) * HH * 64;
      for (int i = t; i < HH * 64; i += 256) xr[i] = 0u;
    }
  }

  const float* xb = x + (size_t)b * 128 * PLANE + h * 112;
  if (lane < 56) {
    const int w0 = 2 * lane;
    #pragma unroll
    for (int i = 0; i < 4; ++i) {
      const int ci0 = (i * 4 + wave) * 8;
      const float* p = xb + (size_t)ci0 * PLANE + w0;
      float2 q0 = *(const float2*)(p);
      float2 q1 = *(const float2*)(p + (size_t)1 * PLANE);
      float2 q2 = *(const float2*)(p + (size_t)2 * PLANE);
      float2 q3 = *(const float2*)(p + (size_t)3 * PLANE);
      float2 q4 = *(const float2*)(p + (size_t)4 * PLANE);
      float2 q5 = *(const float2*)(p + (size_t)5 * PLANE);
      float2 q6 = *(const float2*)(p + (size_t)6 * PLANE);
      float2 q7 = *(const float2*)(p + (size_t)7 * PLANE);
      uint4 dE, dO;
      dE.x = (u32)f2bf(q0.x) | ((u32)f2bf(q1.x) << 16);
      dO.x = (u32)f2bf(q0.y) | ((u32)f2bf(q1.y) << 16);
      dE.y = (u32)f2bf(q2.x) | ((u32)f2bf(q3.x) << 16);
      dO.y = (u32)f2bf(q2.y) | ((u32)f2bf(q3.y) << 16);
      dE.z = (u32)f2bf(q4.x) | ((u32)f2bf(q5.x) << 16);
      dO.z = (u32)f2bf(q4.y) | ((u32)f2bf(q5.y) << 16);
      dE.w = (u32)f2bf(q6.x) | ((u32)f2bf(q7.x) << 16);
      dO.w = (u32)f2bf(q6.y) | ((u32)f2bf(q7.y) << 16);
      *(uint4*)&tile[(size_t)w0 * 68 + ci0 / 2] = dE;
      *(uint4*)&tile[(size_t)(w0 + 1) * 68 + ci0 / 2] = dO;
    }
  }
  __syncthreads();
  const int c = t & 63;
  float s0 = 0.f, s1 = 0.f;
  u32* xg = (u32*)xt + (((size_t)b * HH + h + 1) * HH + 1) * 64;
  #pragma unroll
  for (int j = 0; j < 28; ++j) {
    const int idx = t + 256 * j;
    const int w = idx >> 6;
    const u32 v = tile[w * 68 + c];
    s0 += __uint_as_float(v << 16);
    s1 += __uint_as_float(v & 0xffff0000u);
    xg[(size_t)w * 64 + c] = v;
  }
  psum[wave * 128 + 2 * c] = s0;
  psum[wave * 128 + 2 * c + 1] = s1;
  __syncthreads();
  if (t < 128)
    part[((size_t)h * 32 + b) * 128 + t] =
        psum[t] + psum[128 + t] + psum[256 + t] + psum[384 + t];
}

// ---- fused reduce-over-h + routing. grid 32 (b), 256 thr ----
__global__ __launch_bounds__(256) void reduce_routing_kernel(
    const float* __restrict__ part, const float* __restrict__ rww,
    const float* __restrict__ rwb, float* __restrict__ rw) {
  __shared__ float red[256];
  __shared__ float pl[128];
  const int b = blockIdx.x, t = threadIdx.x;
  const int ci = t & 127, half = t >> 7;
  float s = 0.f;
  const float* p = part + ((size_t)(half * 56) * 32 + b) * 128 + ci;
  #pragma unroll 4
  for (int h = 0; h < 56; ++h) s += p[(size_t)h * 32 * 128];
  red[t] = s;
  __syncthreads();
  if (t < 128) pl[t] = red[t] + red[t + 128];
  __syncthreads();
  const int e = t >> 6, l = t & 63;
  float acc = pl[l] * rww[e * 128 + l] + pl[l + 64] * rww[e * 128 + l + 64];
  #pragma unroll
  for (int off = 32; off > 0; off >>= 1) acc += __shfl_down(acc, off, 64);
  if (l == 0) {
    const float logit = acc * (1.0f / (float)PLANE) + rwb[e];
    rw[b * 4 + e] = 1.0f / (1.0f + expf(-logit));
  }
}

// ---- mix: writes wmix in GEMM-tiled + LDS-swizzled layout ----
// layout: [b][kc=0..35][m=0..255][32 ci], with word-in-row XOR baked:
//   word' = word ^ (((m>>3)&1)<<3 | ((m>>1)&1)<<2)
// so GEMM A-staging is perfectly linear/contiguous and ds_read applies the
// same XOR (T2 swizzle for free; rule 21 both-sides pattern).
__global__ __launch_bounds__(256) void mix_kernel(const float* __restrict__ ew,
                                                  const float* __restrict__ rw,
                                                  u16* __restrict__ wmix) {
  const int t = threadIdx.x;
  const int oc = blockIdx.x * 4 + (t >> 6);
  const int lane = t & 63;
  const int b0 = blockIdx.y * 4;
  const int wsw = (((oc >> 3) & 1) << 3) | (((oc >> 1) & 1) << 2);
  float ereg[4][18];
  #pragma unroll
  for (int e = 0; e < 4; ++e) {
    const float* p = ew + ((size_t)e * 256 + oc) * 1152 + lane * 18;
    #pragma unroll
    for (int j = 0; j < 18; ++j) ereg[e][j] = p[j];
  }
  u32* wmix32 = (u32*)wmix;
  const int kc_lo = lane >> 4;            // which 32-chunk within the tap group
  const int wrd = (lane & 15) ^ wsw;      // swizzled word within row
  for (int bb = 0; bb < 4; ++bb) {
    const int b = b0 + bb;
    const float w0 = rw[b * 4 + 0], w1 = rw[b * 4 + 1];
    const float w2 = rw[b * 4 + 2], w3 = rw[b * 4 + 3];
    u32* dstb = wmix32 + (size_t)b * 36 * 4096 + (size_t)oc * 16 + wrd;
    #pragma unroll
    for (int r = 0; r < 9; ++r) {
      const float va = w0 * ereg[0][r] + w1 * ereg[1][r] + w2 * ereg[2][r] + w3 * ereg[3][r];
      const float vb = w0 * ereg[0][9 + r] + w1 * ereg[1][9 + r] + w2 * ereg[2][9 + r] + w3 * ereg[3][9 + r];
      dstb[(size_t)(r * 4 + kc_lo) * 4096] = (u32)f2bf(va) | ((u32)f2bf(vb) << 16);
    }
  }
}

// ---- 8-phase GEMM, 256x256 tile, 8 waves, counted vmcnt (T3+T4+T2+T5) ----
// grid (32 b, 13 nt), 512 thr. LDS: 4-slot ring x (A 16KB + B 16KB) = 128KB.
// vmcnt never drains to 0 in the loop; FULL vmcnt(0) drain after the loop so
// no wave reaches s_endpgm with in-flight LDS-writing DMA (crash-fix, R4).
__global__ __launch_bounds__(512) void gemm8_kernel(const u16* __restrict__ wmix,
                                                    const u16* __restrict__ xt,
                                                    float* __restrict__ out) {
  __shared__ u16 a_sm[4][8192];   // [slot][m*32 + ci]  (64 KB)
  __shared__ u16 b_sm[4][8192];   // [slot][pix*32 + ci] (64 KB)
  const int b = blockIdx.x, nt = blockIdx.y;
  const int t = threadIdx.x, lane = t & 63, wave = t >> 6;
  const int wm = wave >> 2, wn = wave & 3;     // 2M x 4N wave grid
  const int fr = lane & 15, quad = lane >> 4;
  // T2 read-side swizzle: 16B-granule ^= f(row bits 1,3); row ≡ fr (mod 16)
  const int quadS = quad ^ ((((fr >> 3) & 1) << 1) | ((fr >> 1) & 1));

  // A staging source: tiled+swizzled wmix is linear in (kc, t, rnd)
  const u16* gA = wmix + (size_t)b * EWSTRIDE + (size_t)t * 8;
  // B staging: thread t stages pixels pl0 (rnd0) and pl0+128 (rnd1),
  // 16B granule (t&3), with inverse swizzle folded into the source address.
  const int pl0 = t >> 2, pl1 = pl0 + 128;
  int n0 = nt * 256 + pl0, n1 = nt * 256 + pl1;
  if (n0 > NPIX - 1) n0 = NPIX - 1;
  if (n1 > NPIX - 1) n1 = NPIX - 1;
  const int g0 = (t & 3) ^ ((((pl0 >> 3) & 1) << 1) | ((pl0 >> 1) & 1));
  const int g1 = (t & 3) ^ ((((pl1 >> 3) & 1) << 1) | ((pl1 >> 1) & 1));
  const u16* xtb = xt + (size_t)b * XT_SAMP;
  const u16* pB0 = xtb + ((size_t)(2 * (n0 / 56)) * HH + 2 * (n0 % 56)) * 128 + g0 * 8;
  const u16* pB1 = xtb + ((size_t)(2 * (n1 / 56)) * HH + 2 * (n1 % 56)) * 128 + g1 * 8;
  u16* const laD = &a_sm[0][0] + (size_t)t * 8;
  u16* const lbD = &b_sm[0][0] + (size_t)t * 8;

#define STAGE_A(KP) do {                                                       \
    u16* d_ = laD + (size_t)((KP) & 3) * 8192;                                 \
    const u16* s_ = gA + (size_t)(KP) * 8192;                                  \
    gl_lds16(s_, d_);                                                          \
    gl_lds16(s_ + 4096, d_ + 4096);                                            \
  } while (0)
#define STAGE_B(KP) do {                                                       \
    u16* d_ = lbD + (size_t)((KP) & 3) * 8192;                                 \
    const int rp_ = (KP) >> 2, qp_ = (KP) & 3;                                 \
    const size_t off_ = (size_t)((rp_ / 3) * HH + (rp_ % 3)) * 128 + qp_ * 32; \
    gl_lds16(pB0 + off_, d_);                                                  \
    gl_lds16(pB1 + off_, d_ + 4096);                                           \
  } while (0)

  f32x4 acc[8][4];
  const f32x4 zv = {0.f, 0.f, 0.f, 0.f};
  #pragma unroll
  for (int i = 0; i < 8; ++i)
    #pragma unroll
    for (int j = 0; j < 4; ++j) acc[i][j] = zv;

  // prologue: stage chunks 0..2 chunk-major (so oldest-4 == chunk 0)
  STAGE_A(0); STAGE_B(0);
  STAGE_A(1); STAGE_B(1);
  STAGE_A(2); STAGE_B(2);
  asm volatile("s_waitcnt vmcnt(8)" ::: "memory");
  __builtin_amdgcn_s_barrier();

  for (int kc = 0; kc < 36; ++kc) {
    const int slot = kc & 3;
    int kp = kc + 3; if (kp >= 36) kp -= 36;   // wraparound keeps vmcnt uniform
    const u16* as = &a_sm[slot][0];
    const u16* bs = &b_sm[slot][0];
    bf16x8 av[4], bv[4];
    // ---- P1 ----
    #pragma unroll
    for (int i = 0; i < 4; ++i)
      av[i] = *(const bf16x8*)(as + (wm * 128 + i * 16 + fr) * 32 + quadS * 8);
    #pragma unroll
    for (int j = 0; j < 4; ++j)
      bv[j] = *(const bf16x8*)(bs + (wn * 64 + j * 16 + fr) * 32 + quadS * 8);
    STAGE_A(kp);
    __builtin_amdgcn_s_barrier();
    asm volatile("s_waitcnt lgkmcnt(0)" ::: "memory");
    __builtin_amdgcn_s_setprio(1);
    #pragma unroll
    for (int i = 0; i < 4; ++i)
      #pragma unroll
      for (int j = 0; j < 4; ++j)
        acc[i][j] = __builtin_amdgcn_mfma_f32_16x16x32_bf16(av[i], bv[j], acc[i][j], 0, 0, 0);
    __builtin_amdgcn_s_setprio(0);
    __builtin_amdgcn_s_barrier();
    // ---- P2 ----
    #pragma unroll
    for (int i = 0; i < 4; ++i)
      av[i] = *(const bf16x8*)(as + (wm * 128 + (i + 4) * 16 + fr) * 32 + quadS * 8);
    STAGE_B(kp);
    __builtin_amdgcn_s_barrier();
    asm volatile("s_waitcnt lgkmcnt(0)" ::: "memory");
    __builtin_amdgcn_s_setprio(1);
    #pragma unroll
    for (int i = 0; i < 4; ++i)
      #pragma unroll
      for (int j = 0; j < 4; ++j)
        acc[i + 4][j] = __builtin_amdgcn_mfma_f32_16x16x32_bf16(av[i], bv[j], acc[i + 4][j], 0, 0, 0);
    __builtin_amdgcn_s_setprio(0);
    asm volatile("s_waitcnt vmcnt(8)" ::: "memory");   // chunk kc+1 complete; never 0
    __builtin_amdgcn_s_barrier();
  }
#undef STAGE_A
#undef STAGE_B

  // drain ALL outstanding global_load_lds before any wave can reach s_endpgm:
  // in-flight DMA into deallocated LDS is UB (suspected cause of R3 crash).
  asm volatile("s_waitcnt vmcnt(0)" ::: "memory");
  __builtin_amdgcn_s_barrier();

  float* os = out + (size_t)b * MDIM * NPIX;
  const int mb = wm * 128 + quad * 4;
  const int nb = nt * 256 + wn * 64 + fr;
  #pragma unroll
  for (int j = 0; j < 4; ++j) {
    const int n = nb + j * 16;
    if (n < NPIX) {
      #pragma unroll
      for (int i = 0; i < 8; ++i) {
        const int m = mb + i * 16;
        #pragma unroll
        for (int rr = 0; rr < 4; ++rr)
          os[(size_t)(m + rr) * NPIX + n] = acc[i][j][rr];
      }
    }
  }
}

// ---- fallback path (ws too small): pool + naive direct conv ----
__global__ void routing_kernel(const float* __restrict__ pooled,
                               const float* __restrict__ rww,
                               const float* __restrict__ rwb,
                               float* __restrict__ rw, float scale) {
  const int t = threadIdx.x;
  if (t >= 128) return;
  const int b = t >> 2, e = t & 3;
  float acc = rwb[e];
  for (int c = 0; c < 128; ++c) acc += pooled[b * 128 + c] * scale * rww[e * 128 + c];
  rw[b * 4 + e] = 1.0f / (1.0f + expf(-acc));
}

__global__ __launch_bounds__(256) void pool_kernel(const float* __restrict__ x,
                                                   float* __restrict__ pooled) {
  const int ci = blockIdx.x, b = blockIdx.y;
  const float4* p = (const float4*)(x + ((size_t)b * 128 + ci) * PLANE);
  float s = 0.f;
  for (int i = threadIdx.x; i < PLANE / 4; i += 256) {
    float4 v = p[i];
    s += v.x + v.y + v.z + v.w;
  }
  #pragma unroll
  for (int off = 32; off > 0; off >>= 1) s += __shfl_down(s, off, 64);
  __shared__ float red[4];
  if ((threadIdx.x & 63) == 0) red[threadIdx.x >> 6] = s;
  __syncthreads();
  if (threadIdx.x == 0)
    pooled[b * 128 + ci] = (red[0] + red[1] + red[2] + red[3]) * (1.0f / (float)PLANE);
}

__global__ __launch_bounds__(256) void naive_conv(const float* __restrict__ x,
                                                  const float* __restrict__ ew,
                                                  const float* __restrict__ rw,
                                                  float* __restrict__ out) {
  const size_t idx = (size_t)blockIdx.x * 256 + threadIdx.x;
  if (idx >= (size_t)32 * MDIM * NPIX) return;
  const int n = (int)(idx % NPIX);
  const int tmp = (int)(idx / NPIX);
  const int oc = tmp % MDIM;
  const int b = tmp / MDIM;
  const int oh = n / 56, ow = n % 56;
  const float w0 = rw[b * 4 + 0], w1 = rw[b * 4 + 1];
  const float w2 = rw[b * 4 + 2], w3 = rw[b * 4 + 3];
  float acc = 0.f;
  for (int ci = 0; ci < 128; ++ci) {
    const float* xp = x + ((size_t)b * 128 + ci) * PLANE;
    const size_t wb = ((size_t)oc * 128 + ci) * 9;
    for (int kh = 0; kh < 3; ++kh) {
      const int ih = 2 * oh - 1 + kh;
      if (ih < 0 || ih >= 112) continue;
      for (int kw = 0; kw < 3; ++kw) {
        const int iw = 2 * ow - 1 + kw;
        if (iw < 0 || iw >= 112) continue;
        const int ko = kh * 3 + kw;
        const float wsum = w0 * ew[wb + ko] + w1 * ew[(size_t)EWSTRIDE + wb + ko]
                         + w2 * ew[2 * (size_t)EWSTRIDE + wb + ko]
                         + w3 * ew[3 * (size_t)EWSTRIDE + wb + ko];
        acc += xp[ih * 112 + iw] * wsum;
      }
    }
  }
  out[idx] = acc;
}

extern "C" void kernel_launch(void* const* d_in, const int* in_sizes, int n_in,
                              void* d_out, int out_size, void* d_ws, size_t ws_size,
                              hipStream_t stream) {
  const float* x   = (const float*)d_in[0];
  const float* rww = (const float*)d_in[1];
  const float* rwb = (const float*)d_in[2];
  const float* ew  = (const float*)d_in[3];
  float* out = (float*)d_out;

  const size_t xt_bytes = 32 * XT_SAMP * 2;                     // 106,463,232
  const size_t wmix_off = xt_bytes;
  const size_t part_off = wmix_off + (size_t)32 * EWSTRIDE * 2; // +18,874,368
  const size_t pooled_off = part_off + (size_t)112 * 32 * 128 * 4;  // +1,835,008
  const size_t rw_off = pooled_off + 16384;
  const size_t need = rw_off + 512;

  if (ws_size >= need) {
    u16* xt = (u16*)d_ws;
    u16* wmix = (u16*)((char*)d_ws + wmix_off);
    float* part = (float*)((char*)d_ws + part_off);
    float* rw_ws = (float*)((char*)d_ws + rw_off);
    transpose_pool_kernel<<<dim3(112, 32), 256, 0, stream>>>(x, xt, part);
    reduce_routing_kernel<<<32, 256, 0, stream>>>(part, rww, rwb, rw_ws);
    mix_kernel<<<dim3(64, 8), 256, 0, stream>>>(ew, rw_ws, wmix);
    gemm8_kernel<<<dim3(32, 13), 512, 0, stream>>>(wmix, xt, out);
  } else {
    float* pooled = (float*)d_ws;
    float* rw_ws = (float*)((char*)d_ws + 16384);
    pool_kernel<<<dim3(128, 32), 256, 0, stream>>>(x, pooled);
    routing_kernel<<<1, 128, 0, stream>>>(pooled, rww, rwb, rw_ws, 1.0f);
    naive_conv<<<(int)(((size_t)32 * MDIM * NPIX + 255) / 256), 256, 0, stream>>>(
        x, ew, rw_ws, out);
  }
}